// Round 7
// baseline (2263.391 us; speedup 1.0000x reference)
//
#include <hip/hip_runtime.h>
#include <cstdint>
#include <cstddef>

// Problem constants (match reference)
#define S_LEN 256
#define BB    32
#define EMBD  256
#define HID   256
#define NTAG  10
#define L_TOT (BB*S_LEN)      // 8192 flattened viterbi length
#define NEGV  -10000.0f
#define SOS_I 1
#define EOS_I 2

__device__ __forceinline__ float sigf(float x) { return 1.0f / (1.0f + expf(-x)); }

// ---------------------------------------------------------------------------
// prep: gather embeddings E[t*32+b][m] = emb[x[b][t]][m]
// ---------------------------------------------------------------------------
__global__ void prep_ebuf(const int* __restrict__ x, const float* __restrict__ emb,
                          float* __restrict__ E) {
    const int row = blockIdx.x;          // t*32 + b
    const int t = row >> 5, b = row & 31;
    const int xi = x[b * S_LEN + t];
    E[(size_t)row * EMBD + threadIdx.x] = emb[(size_t)xi * EMBD + threadIdx.x];
}

// prep: Wt[d][k][j], k<256 -> Wih_d[j][k], k>=256 -> Whh_d[j][k-256]  (k-major)
__global__ void prep_wt(const float* __restrict__ Wih_f, const float* __restrict__ Whh_f,
                        const float* __restrict__ Wih_b, const float* __restrict__ Whh_b,
                        float* __restrict__ Wt) {
    const int dk = blockIdx.x;           // d*512 + k
    const int d = dk >> 9, k = dk & 511;
    const int j = threadIdx.x;           // 0..1023
    const float* src = (d == 0) ? ((k < 256) ? Wih_f : Whh_f)
                                : ((k < 256) ? Wih_b : Whh_b);
    const int kk = k & 255;
    Wt[(size_t)dk * 1024 + j] = src[(size_t)j * 256 + kk];
}

__global__ void prep_bias(const float* __restrict__ bih_f, const float* __restrict__ bhh_f,
                          const float* __restrict__ bih_b, const float* __restrict__ bhh_b,
                          float* __restrict__ bc) {
    const int idx = blockIdx.x * blockDim.x + threadIdx.x; // 0..2047
    if (idx < 1024) bc[idx] = bih_f[idx] + bhh_f[idx];
    else            bc[idx] = bih_b[idx - 1024] + bhh_b[idx - 1024];
}

// ---------------------------------------------------------------------------
// Persistent BiLSTM recurrence, round-7 schedule: ONE barrier per step.
// 256 blocks x 1024 thr. group g=blk&15 -> (d,bg: 4 batches); member mg=blk>>4.
// Waves 0-7 = e-part k-slices (k=wave*32), waves 8-15 = h-part (k=256+wh*32).
// Double-buffered part[] (by step parity): after barrier(s),
//   wave0: post(s) -> h atomic-stores -> vmcnt(0) -> flag(s+1), then its own
//          e-compute for s+1;
//   e-waves: compute part_e(s+1) from E directly (uniform global loads, no LDS);
//   h-waves: poll ONLY their 2 member flags, 2 coalesced agent-atomic h loads
//            per lane -> per-wave LDS ministage -> 8 uniform b128 reads -> fma.
// The whole post->flag->poll->load RTT hides under e-wave compute.
// ---------------------------------------------------------------------------
__global__ __launch_bounds__(1024) void lstm_rec(
    const float* __restrict__ E,      // [8192 rows t*32+b][256]
    const float* __restrict__ Wt,     // [2][512 fused k][1024 j]
    const float* __restrict__ bc,     // [2][1024]
    float* __restrict__ hh,           // [2][256 s][32 b][256 m]
    unsigned int* __restrict__ flags) {  // [16 groups][16 members]
    const int blk = blockIdx.x;
    const int g   = blk & 15;
    const int mg  = blk >> 4;
    const int d   = g >> 3;
    const int bg  = g & 7;
    const int tid = threadIdx.x;
    const int wave = __builtin_amdgcn_readfirstlane(tid >> 6);  // 0..15
    const int lane = tid & 63;
    const bool is_h = wave >= 8;
    const int wh = wave & 7;
    const int kb = wave * 32;                // fused-k base (h-waves: 256+wh*32)
    const int jg = (lane >> 4) * 256 + mg * 16 + (lane & 15);

    // persistent weights: w[i] = Wt[d][kb+i][jg]   (32 VGPRs)
    float w[32];
    {
        const float* wsrc = Wt + ((size_t)d * 512 + kb) * 1024 + jg;
        #pragma unroll
        for (int i = 0; i < 32; ++i) w[i] = wsrc[(size_t)i * 1024];
    }

    __shared__ float part[2][16][4][68];     // [buf][wave][b_local][lane(64)+pad]
    __shared__ float hst[8][4][32];          // per-h-wave ministage [wh][b][kk]
    __shared__ float cst[4][16];
    __shared__ float bias[64];
    if (tid < 64) bias[tid] = bc[d * 1024 + (tid >> 4) * 256 + mg * 16 + (tid & 15)];

    unsigned int* fl = flags + g * 16;

    // ---- prologue: part(0) ----
    {
        float acc[4] = {0.f, 0.f, 0.f, 0.f};
        if (!is_h) {
            const int t0 = d ? (S_LEN - 1) : 0;
            #pragma unroll 2
            for (int i = 0; i < 8; ++i) {
                #pragma unroll
                for (int b = 0; b < 4; ++b) {
                    const float4 v = *(const float4*)&E[((size_t)t0 * 32 + bg * 4 + b) * 256 + kb + i * 4];
                    acc[b] = fmaf(v.x, w[i * 4 + 0], acc[b]);
                    acc[b] = fmaf(v.y, w[i * 4 + 1], acc[b]);
                    acc[b] = fmaf(v.z, w[i * 4 + 2], acc[b]);
                    acc[b] = fmaf(v.w, w[i * 4 + 3], acc[b]);
                }
            }
        }
        #pragma unroll
        for (int b = 0; b < 4; ++b) part[0][wave][b][lane] = acc[b];
    }

    #pragma unroll 1
    for (int s = 0; s < S_LEN; ++s) {
        __syncthreads();   // part[s&1] complete; previous buffer free

        // ---- wave0: post(s) + signal ----
        if (tid < 64) {
            const int bl = tid >> 4, m = tid & 15;
            const int cb = s & 1;
            float vg[4];
            #pragma unroll
            for (int gg = 0; gg < 4; ++gg) {
                float v = bias[gg * 16 + m];
                #pragma unroll
                for (int q = 0; q < 16; ++q) v += part[cb][q][bl][gg * 16 + m];
                vg[gg] = v;
            }
            const float iv = sigf(vg[0]);
            const float fv = sigf(vg[1]);
            const float gv = tanhf(vg[2]);
            const float ov = sigf(vg[3]);
            float c = (s == 0) ? 0.f : cst[bl][m];
            c = fv * c + iv * gv;
            cst[bl][m] = c;
            const float hv = ov * tanhf(c);
            __hip_atomic_store(
                &hh[(((size_t)d * S_LEN + s) * 32 + (bg * 4 + bl)) * 256 + mg * 16 + m],
                hv, __ATOMIC_RELAXED, __HIP_MEMORY_SCOPE_AGENT);
            if (s < S_LEN - 1) {
                // wave-local: all 64 h-stores (this wave's) reach coherence point
                asm volatile("s_waitcnt vmcnt(0)" ::: "memory");
                if (tid == 0)
                    __hip_atomic_store(&fl[mg], (unsigned)(s + 1),
                                       __ATOMIC_RELAXED, __HIP_MEMORY_SCOPE_AGENT);
            }
        }

        if (s < S_LEN - 1) {
            const int nb = (s + 1) & 1;
            float acc[4] = {0.f, 0.f, 0.f, 0.f};
            if (!is_h) {
                // e-part of step s+1: direct uniform global reads (L2/L3-resident)
                const int t1 = d ? (S_LEN - 2 - s) : (s + 1);
                #pragma unroll 2
                for (int i = 0; i < 8; ++i) {
                    #pragma unroll
                    for (int b = 0; b < 4; ++b) {
                        const float4 v = *(const float4*)&E[((size_t)t1 * 32 + bg * 4 + b) * 256 + kb + i * 4];
                        acc[b] = fmaf(v.x, w[i * 4 + 0], acc[b]);
                        acc[b] = fmaf(v.y, w[i * 4 + 1], acc[b]);
                        acc[b] = fmaf(v.z, w[i * 4 + 2], acc[b]);
                        acc[b] = fmaf(v.w, w[i * 4 + 3], acc[b]);
                    }
                }
            } else {
                // poll ONLY this wave's 2 member flags (m in [wh*32, wh*32+32))
                const unsigned tgt = (unsigned)(s + 1);
                while (true) {
                    unsigned v = tgt;
                    if (lane < 2)
                        v = __hip_atomic_load(&fl[wh * 2 + lane], __ATOMIC_RELAXED, __HIP_MEMORY_SCOPE_AGENT);
                    if (__all((int)(v >= tgt))) break;
                }
                asm volatile("" ::: "memory");   // keep h loads below the poll
                // coalesced per-lane h(s) loads (agent atomics bypass stale L1)
                const int bl = lane >> 4, kk = (lane & 15) * 2;
                const float* hrow = hh + (((size_t)d * S_LEN + s) * 32 + bg * 4 + bl) * 256
                                    + wh * 32 + kk;
                const float h0 = __hip_atomic_load(hrow,     __ATOMIC_RELAXED, __HIP_MEMORY_SCOPE_AGENT);
                const float h1 = __hip_atomic_load(hrow + 1, __ATOMIC_RELAXED, __HIP_MEMORY_SCOPE_AGENT);
                hst[wh][bl][kk]     = h0;
                hst[wh][bl][kk + 1] = h1;
                // same-wave ds_write -> ds_read: compiler inserts lgkmcnt
                #pragma unroll 2
                for (int i = 0; i < 8; ++i) {
                    #pragma unroll
                    for (int b = 0; b < 4; ++b) {
                        const float4 v = *(const float4*)&hst[wh][b][i * 4];  // uniform: broadcast
                        acc[b] = fmaf(v.x, w[i * 4 + 0], acc[b]);
                        acc[b] = fmaf(v.y, w[i * 4 + 1], acc[b]);
                        acc[b] = fmaf(v.z, w[i * 4 + 2], acc[b]);
                        acc[b] = fmaf(v.w, w[i * 4 + 3], acc[b]);
                    }
                }
            }
            #pragma unroll
            for (int b = 0; b < 4; ++b) part[nb][wave][b][lane] = acc[b];
        }
    }
}

// ---------------------------------------------------------------------------
// out[r][tag] = [hf | hb] . Wout[tag] + bout[tag],  r = b*256 + t
// ---------------------------------------------------------------------------
__global__ __launch_bounds__(128) void out_proj(const float* __restrict__ hh,
                                                const float* __restrict__ Wout,
                                                const float* __restrict__ bout,
                                                float* __restrict__ out) {
    const int r = blockIdx.x * blockDim.x + threadIdx.x; // 0..8191
    const int b = r >> 8, t = r & 255;
    const float* hf = hh + (((size_t)0 * S_LEN + t) * 32 + b) * 256;
    const float* hb = hh + (((size_t)1 * S_LEN + (S_LEN - 1 - t)) * 32 + b) * 256;
    float acc[NTAG];
    #pragma unroll
    for (int q = 0; q < NTAG; ++q) acc[q] = bout[q];
    for (int m = 0; m < HID; ++m) {
        const float hv = hf[m];
        #pragma unroll
        for (int q = 0; q < NTAG; ++q) acc[q] = fmaf(hv, Wout[q * 512 + m], acc[q]);
    }
    for (int m = 0; m < HID; ++m) {
        const float hv = hb[m];
        #pragma unroll
        for (int q = 0; q < NTAG; ++q) acc[q] = fmaf(hv, Wout[q * 512 + 256 + m], acc[q]);
    }
    #pragma unroll
    for (int q = 0; q < NTAG; ++q) out[(size_t)r * NTAG + q] = acc[q];
}

// ---------------------------------------------------------------------------
// Viterbi forward values (sequential, exact reference arithmetic per step).
// Lanes 0..9 = 'to'. readlane->SGPR broadcast; max tree shaped for v_max3.
// ---------------------------------------------------------------------------
__global__ __launch_bounds__(64) void viterbi_fv(const float* __restrict__ feats,
                                                 const float* __restrict__ trans,
                                                 float* __restrict__ fvh,
                                                 float* __restrict__ score_out,
                                                 int* __restrict__ best_out) {
    const int lane = threadIdx.x;
    float trow[NTAG];
    #pragma unroll
    for (int f = 0; f < NTAG; ++f) trow[f] = (lane < NTAG) ? trans[lane * NTAG + f] : -3.0e38f;
    float fv[NTAG];
    #pragma unroll
    for (int f = 0; f < NTAG; ++f) fv[f] = (f == SOS_I) ? 0.f : NEGV;
    float fq[8];
    #pragma unroll
    for (int q = 0; q < 8; ++q) fq[q] = (lane < NTAG) ? feats[q * NTAG + lane] : 0.f;

    for (int r8 = 0; r8 < L_TOT; r8 += 8) {
        #pragma unroll
        for (int q = 0; q < 8; ++q) {
            const int r = r8 + q;
            float sc[NTAG];
            #pragma unroll
            for (int f = 0; f < NTAG; ++f) sc[f] = fv[f] + trow[f];
            // nested fmaxf groups fuse to v_max3_f32 (4 max3 + 1 fmax, depth 3)
            const float m1 = fmaxf(fmaxf(sc[0], sc[1]), sc[2]);
            const float m2 = fmaxf(fmaxf(sc[3], sc[4]), sc[5]);
            const float m3 = fmaxf(fmaxf(sc[6], sc[7]), sc[8]);
            const float m  = fmaxf(fmaxf(fmaxf(m1, m2), m3), sc[9]);
            const float fvnew = m + fq[q];
            if (lane < NTAG) fvh[(size_t)r * NTAG + lane] = fvnew;
            const int rn = r + 8;
            fq[q] = (rn < L_TOT && lane < NTAG) ? feats[(size_t)rn * NTAG + lane] : 0.f;
            #pragma unroll
            for (int f = 0; f < NTAG; ++f)
                fv[f] = __uint_as_float(__builtin_amdgcn_readlane(__float_as_uint(fvnew), f));
        }
    }

    if (lane == 0) {
        float bm = fv[0] + trans[EOS_I * NTAG + 0];
        int ba = 0;
        #pragma unroll
        for (int f = 1; f < NTAG; ++f) {
            const float tv = fv[f] + trans[EOS_I * NTAG + f];
            if (tv > bm) { bm = tv; ba = f; }   // strict > => first-max tie rule
        }
        score_out[0] = bm;
        best_out[0] = ba;
    }
}

// Backpointers, fully parallel: bptr[r][to] = first-argmax_f (fv[r-1][f] + T[to][f])
__global__ void viterbi_bp(const float* __restrict__ fvh, const float* __restrict__ trans,
                           unsigned char* __restrict__ bp) {
    const int idx = blockIdx.x * blockDim.x + threadIdx.x;
    if (idx >= L_TOT * NTAG) return;
    const int r = idx / NTAG, to = idx - r * NTAG;
    float best = 0.f;
    int arg = 0;
    #pragma unroll
    for (int f = 0; f < NTAG; ++f) {
        const float fp = r ? fvh[(size_t)(r - 1) * NTAG + f] : ((f == SOS_I) ? 0.f : NEGV);
        const float s = fp + trans[to * NTAG + f];
        if (f == 0) best = s;
        else if (s > best) { best = s; arg = f; }  // strict > => first-max
    }
    bp[idx] = (unsigned char)arg;
}

// Chunked backtrace (exact function-composition scan over [10]->[10] maps)
__global__ __launch_bounds__(1024) void backtrace(const unsigned char* __restrict__ bp,
                                                  const int* __restrict__ best_in,
                                                  float* __restrict__ path_out) {
    __shared__ unsigned char fc[128 * NTAG];
    __shared__ unsigned char topt[128];
    const int tid = threadIdx.x;
    for (int pe = tid; pe < 128 * NTAG; pe += 1024) {
        const int c = pe / NTAG, e = pe - c * NTAG;
        int cur = e;
        for (int i = 63; i >= 0; --i) cur = bp[(size_t)(c * 64 + i) * NTAG + cur];
        fc[c * NTAG + e] = (unsigned char)cur;
    }
    __syncthreads();
    if (tid == 0) {
        int carry = best_in[0];
        for (int c = 127; c >= 0; --c) {
            topt[c] = (unsigned char)carry;
            carry = fc[c * NTAG + carry];
        }
    }
    __syncthreads();
    for (int c = tid; c < 128; c += 1024) {
        int cur = topt[c];
        for (int i = 63; i >= 0; --i) {
            const int t = c * 64 + i;
            path_out[t] = (float)cur;
            cur = bp[(size_t)t * NTAG + cur];
        }
    }
}

// ---------------------------------------------------------------------------
extern "C" void kernel_launch(void* const* d_in, const int* in_sizes, int n_in,
                              void* d_out, int out_size, void* d_ws, size_t ws_size,
                              hipStream_t stream) {
    const int*   x     = (const int*)d_in[0];
    const float* emb   = (const float*)d_in[3];
    const float* Wih_f = (const float*)d_in[4];
    const float* Whh_f = (const float*)d_in[5];
    const float* bih_f = (const float*)d_in[6];
    const float* bhh_f = (const float*)d_in[7];
    const float* Wih_b = (const float*)d_in[8];
    const float* Whh_b = (const float*)d_in[9];
    const float* bih_b = (const float*)d_in[10];
    const float* bhh_b = (const float*)d_in[11];
    const float* Wout  = (const float*)d_in[12];
    const float* bout  = (const float*)d_in[13];
    const float* trans = (const float*)d_in[14];

    char* ws = (char*)d_ws;
    size_t off = 0;
    auto alloc = [&](size_t bytes) { void* p = ws + off; off += (bytes + 255) & ~(size_t)255; return p; };
    unsigned*      flags = (unsigned*)alloc(16 * 16 * 4);                 // 1 KB
    int*           best  = (int*)alloc(256);
    float*         E     = (float*)alloc((size_t)L_TOT * EMBD * 4);       // 8.4 MB
    float*         Wt    = (float*)alloc((size_t)2 * 512 * 1024 * 4);     // 4 MB
    float*         bc    = (float*)alloc(2048 * 4);
    float*         hh    = (float*)alloc((size_t)2 * S_LEN * BB * HID * 4); // 16.8 MB
    float*         fvh   = (float*)alloc((size_t)L_TOT * NTAG * 4);       // 328 KB
    unsigned char* bp    = (unsigned char*)alloc((size_t)L_TOT * NTAG);   // 80 KB

    float* out   = (float*)d_out;                  // [0 .. 81920)
    float* score = out + (size_t)L_TOT * NTAG;     // [81920]
    float* path  = score + 1;                      // [81921 .. 90113)

    (void)hipMemsetAsync(flags, 0, 16 * 16 * 4, stream);  // flags must start at 0 every call
    hipLaunchKernelGGL(prep_ebuf, dim3(L_TOT), dim3(EMBD), 0, stream, x, emb, E);
    hipLaunchKernelGGL(prep_wt,   dim3(1024),  dim3(1024), 0, stream, Wih_f, Whh_f, Wih_b, Whh_b, Wt);
    hipLaunchKernelGGL(prep_bias, dim3(2),     dim3(1024), 0, stream, bih_f, bhh_f, bih_b, bhh_b, bc);
    hipLaunchKernelGGL(lstm_rec,  dim3(256),   dim3(1024), 0, stream, E, Wt, bc, hh, flags);
    hipLaunchKernelGGL(out_proj,  dim3(L_TOT / 128), dim3(128), 0, stream, hh, Wout, bout, out);
    hipLaunchKernelGGL(viterbi_fv, dim3(1),    dim3(64),   0, stream, out, trans, fvh, score, best);
    hipLaunchKernelGGL(viterbi_bp, dim3((L_TOT * NTAG + 255) / 256), dim3(256), 0, stream, fvh, trans, bp);
    hipLaunchKernelGGL(backtrace, dim3(1),     dim3(1024), 0, stream, bp, best, path);
}